// Round 1
// baseline (1643.705 us; speedup 1.0000x reference)
//
#include <hip/hip_runtime.h>
#include <cstdint>
#include <cstddef>

#define HEADS 12
#define HD    64
#define NB    4
#define SEQ   2048
#define DIM   768
#define NQKV  2304

static constexpr float SCALE = 0.28867513459481287f; // 1/sqrt(12) (per reference: 1/sqrt(HEADS))

// ---------------------------------------------------------------------------
// Kernel 1: QKV projection GEMM.  C[8192][2304] = x[8192][768] @ w[768][2304] + b
// 128x128 tile, BK=16, 256 threads, 8x8 micro-tile as 2x2 blocks of 4x4 (float4).
// Epilogue scatters into Q/K/V buffers laid out [B, H, S, 64] (fp32).
// ---------------------------------------------------------------------------
__global__ __launch_bounds__(256) void qkv_gemm_kernel(
    const float* __restrict__ x, const float* __restrict__ w,
    const float* __restrict__ bias, float* __restrict__ qkv_ws)
{
    __shared__ __align__(16) float As[16][132]; // stored transposed: As[k][m]
    __shared__ __align__(16) float Bs[16][132]; // Bs[k][n]

    const int tid = threadIdx.x;
    const int tx = tid & 15, ty = tid >> 4;
    const int m0 = blockIdx.y * 128;
    const int n0 = blockIdx.x * 128;

    float acc[2][2][4][4] = {};

    for (int k0 = 0; k0 < DIM; k0 += 16) {
        // A tile: 128 rows x 16 k  (512 float4, 2 per thread), transpose into LDS
        #pragma unroll
        for (int it = 0; it < 2; ++it) {
            int v = tid + it * 256;
            int m = v >> 2;
            int kk = (v & 3) * 4;
            const float4 a = *reinterpret_cast<const float4*>(
                &x[(size_t)(m0 + m) * DIM + k0 + kk]);
            As[kk + 0][m] = a.x; As[kk + 1][m] = a.y;
            As[kk + 2][m] = a.z; As[kk + 3][m] = a.w;
        }
        // B tile: 16 k x 128 cols (512 float4, 2 per thread)
        #pragma unroll
        for (int it = 0; it < 2; ++it) {
            int v = tid + it * 256;
            int k = v >> 5;
            int n = (v & 31) * 4;
            *reinterpret_cast<float4*>(&Bs[k][n]) =
                *reinterpret_cast<const float4*>(&w[(size_t)(k0 + k) * NQKV + n0 + n]);
        }
        __syncthreads();

        #pragma unroll
        for (int k = 0; k < 16; ++k) {
            const float4 a0 = *reinterpret_cast<const float4*>(&As[k][ty * 4]);
            const float4 a1 = *reinterpret_cast<const float4*>(&As[k][64 + ty * 4]);
            const float4 b0 = *reinterpret_cast<const float4*>(&Bs[k][tx * 4]);
            const float4 b1 = *reinterpret_cast<const float4*>(&Bs[k][64 + tx * 4]);
            const float av[2][4] = {{a0.x, a0.y, a0.z, a0.w}, {a1.x, a1.y, a1.z, a1.w}};
            const float bv[2][4] = {{b0.x, b0.y, b0.z, b0.w}, {b1.x, b1.y, b1.z, b1.w}};
            #pragma unroll
            for (int ii = 0; ii < 2; ++ii)
                #pragma unroll
                for (int jj = 0; jj < 2; ++jj)
                    #pragma unroll
                    for (int i = 0; i < 4; ++i)
                        #pragma unroll
                        for (int j = 0; j < 4; ++j)
                            acc[ii][jj][i][j] = fmaf(av[ii][i], bv[jj][j], acc[ii][jj][i][j]);
        }
        __syncthreads();
    }

    // Epilogue: bias + scatter to Q/K/V [which][B,H,S,HD]
    const size_t QSZ = (size_t)NB * HEADS * SEQ * HD;
    #pragma unroll
    for (int ii = 0; ii < 2; ++ii) {
        #pragma unroll
        for (int jj = 0; jj < 2; ++jj) {
            const int nb = n0 + jj * 64 + tx * 4;       // column base (4 contiguous)
            const int which = nb / DIM;                  // 0=q 1=k 2=v
            const int rem = nb - which * DIM;
            const int h = rem >> 6;
            const int dh = rem & 63;
            const float4 bb = *reinterpret_cast<const float4*>(&bias[nb]);
            #pragma unroll
            for (int i = 0; i < 4; ++i) {
                const int m = m0 + ii * 64 + ty * 4 + i;
                const int b_ = m >> 11;
                const int s_ = m & 2047;
                float4 r;
                r.x = acc[ii][jj][i][0] + bb.x;
                r.y = acc[ii][jj][i][1] + bb.y;
                r.z = acc[ii][jj][i][2] + bb.z;
                r.w = acc[ii][jj][i][3] + bb.w;
                float* dst = qkv_ws + which * QSZ +
                             (((size_t)(b_ * HEADS + h) * SEQ + s_) << 6) + dh;
                *reinterpret_cast<float4*>(dst) = r;
            }
        }
    }
}

// ---------------------------------------------------------------------------
// Kernel 2: flash attention, fp32.  One block = one (b,h) x 64 q-rows.
// 256 threads, 4x4 micro-tiles.  Online softmax, row state in 16-lane groups.
// Writes ctx in [B, S, D] layout (d = h*64 + dh) so out_gemm is a plain GEMM.
// ---------------------------------------------------------------------------
__global__ __launch_bounds__(256) void attn_kernel(
    const float* __restrict__ qkv_ws, float* __restrict__ ctx)
{
    const size_t QSZ = (size_t)NB * HEADS * SEQ * HD;
    const int bh = blockIdx.y;            // b*HEADS + h
    const int q0 = blockIdx.x * 64;
    const float* __restrict__ Qh = qkv_ws + (size_t)bh * SEQ * HD;
    const float* __restrict__ Kh = qkv_ws + QSZ + (size_t)bh * SEQ * HD;
    const float* __restrict__ Vh = qkv_ws + 2 * QSZ + (size_t)bh * SEQ * HD;

    __shared__ __align__(16) float Qs[64][68];
    __shared__ __align__(16) float Ks[64][64];  // XOR-swizzled per 4-float chunk
    __shared__ __align__(16) float Vs[64][68];
    __shared__ __align__(16) float Ps[64][65];

    const int tid = threadIdx.x;
    const int tx = tid & 15, ty = tid >> 4;

    // Load Q tile (pre-scaled)
    #pragma unroll
    for (int it = 0; it < 4; ++it) {
        int v = tid + it * 256;
        int q = v >> 4;
        int d0 = (v & 15) * 4;
        const float4 a = *reinterpret_cast<const float4*>(&Qh[(size_t)(q0 + q) * HD + d0]);
        Qs[q][d0 + 0] = a.x * SCALE; Qs[q][d0 + 1] = a.y * SCALE;
        Qs[q][d0 + 2] = a.z * SCALE; Qs[q][d0 + 3] = a.w * SCALE;
    }

    float acc[4][4] = {};
    float m_old[4], l_run[4];
    #pragma unroll
    for (int i = 0; i < 4; ++i) { m_old[i] = -INFINITY; l_run[i] = 0.0f; }

    for (int jt = 0; jt < SEQ / 64; ++jt) {
        const int kb = jt * 64;
        __syncthreads();  // protect Ks/Vs/Ps from previous iteration's readers
        #pragma unroll
        for (int it = 0; it < 4; ++it) {
            int v = tid + it * 256;
            int r = v >> 4;
            int d0 = (v & 15) * 4;
            const float4 kv = *reinterpret_cast<const float4*>(&Kh[(size_t)(kb + r) * HD + d0]);
            const int c4 = (((d0 >> 2) ^ (r & 15)) << 2);
            *reinterpret_cast<float4*>(&Ks[r][c4]) = kv;
            const float4 vv = *reinterpret_cast<const float4*>(&Vh[(size_t)(kb + r) * HD + d0]);
            *reinterpret_cast<float4*>(&Vs[r][d0]) = vv;
        }
        __syncthreads();

        // scores: sc[i][j] = Q[q_i] . K[k_j]
        float sc[4][4] = {};
        #pragma unroll
        for (int d0 = 0; d0 < HD; d0 += 4) {
            float4 qv[4], kv[4];
            #pragma unroll
            for (int i = 0; i < 4; ++i)
                qv[i] = *reinterpret_cast<const float4*>(&Qs[ty * 4 + i][d0]);
            #pragma unroll
            for (int j = 0; j < 4; ++j) {
                const int r = tx * 4 + j;
                const int c4 = (((d0 >> 2) ^ (r & 15)) << 2);
                kv[j] = *reinterpret_cast<const float4*>(&Ks[r][c4]);
            }
            #pragma unroll
            for (int i = 0; i < 4; ++i)
                #pragma unroll
                for (int j = 0; j < 4; ++j)
                    sc[i][j] = fmaf(qv[i].x, kv[j].x,
                               fmaf(qv[i].y, kv[j].y,
                               fmaf(qv[i].z, kv[j].z,
                               fmaf(qv[i].w, kv[j].w, sc[i][j]))));
        }

        // online softmax (row = q-row, shared by the 16 lanes of this tx-group)
        float p[4][4];
        #pragma unroll
        for (int i = 0; i < 4; ++i) {
            float mx = fmaxf(fmaxf(sc[i][0], sc[i][1]), fmaxf(sc[i][2], sc[i][3]));
            #pragma unroll
            for (int off = 1; off < 16; off <<= 1)
                mx = fmaxf(mx, __shfl_xor(mx, off));
            const float m_new = fmaxf(m_old[i], mx);
            float rs = 0.0f;
            #pragma unroll
            for (int j = 0; j < 4; ++j) {
                p[i][j] = __expf(sc[i][j] - m_new);
                rs += p[i][j];
            }
            #pragma unroll
            for (int off = 1; off < 16; off <<= 1)
                rs += __shfl_xor(rs, off);
            const float alpha = __expf(m_old[i] - m_new);  // first iter: exp(-inf)=0
            l_run[i] = l_run[i] * alpha + rs;
            m_old[i] = m_new;
            #pragma unroll
            for (int j = 0; j < 4; ++j) acc[i][j] *= alpha;
        }

        // stage P
        #pragma unroll
        for (int i = 0; i < 4; ++i)
            #pragma unroll
            for (int j = 0; j < 4; ++j)
                Ps[ty * 4 + i][tx * 4 + j] = p[i][j];
        __syncthreads();

        // acc += P @ V
        #pragma unroll
        for (int k = 0; k < 64; ++k) {
            const float4 vv = *reinterpret_cast<const float4*>(&Vs[k][tx * 4]);
            float pk[4];
            #pragma unroll
            for (int i = 0; i < 4; ++i) pk[i] = Ps[ty * 4 + i][k];
            #pragma unroll
            for (int i = 0; i < 4; ++i) {
                acc[i][0] = fmaf(pk[i], vv.x, acc[i][0]);
                acc[i][1] = fmaf(pk[i], vv.y, acc[i][1]);
                acc[i][2] = fmaf(pk[i], vv.z, acc[i][2]);
                acc[i][3] = fmaf(pk[i], vv.w, acc[i][3]);
            }
        }
    }

    // epilogue: normalize and write ctx[B,S,D] with d = h*64+dh
    const int b_ = bh / HEADS;
    const int h = bh - b_ * HEADS;
    #pragma unroll
    for (int i = 0; i < 4; ++i) {
        const float inv = 1.0f / l_run[i];
        float4 r;
        r.x = acc[i][0] * inv; r.y = acc[i][1] * inv;
        r.z = acc[i][2] * inv; r.w = acc[i][3] * inv;
        const int s_ = q0 + ty * 4 + i;
        *reinterpret_cast<float4*>(
            &ctx[((size_t)b_ * SEQ + s_) * DIM + h * HD + tx * 4]) = r;
    }
}

// ---------------------------------------------------------------------------
// Kernel 3: output projection GEMM. out[8192][768] = ctx[8192][768] @ w[768][768] + b
// ---------------------------------------------------------------------------
__global__ __launch_bounds__(256) void out_gemm_kernel(
    const float* __restrict__ ctx, const float* __restrict__ w,
    const float* __restrict__ bias, float* __restrict__ out)
{
    __shared__ __align__(16) float As[16][132];
    __shared__ __align__(16) float Bs[16][132];

    const int tid = threadIdx.x;
    const int tx = tid & 15, ty = tid >> 4;
    const int m0 = blockIdx.y * 128;
    const int n0 = blockIdx.x * 128;

    float acc[2][2][4][4] = {};

    for (int k0 = 0; k0 < DIM; k0 += 16) {
        #pragma unroll
        for (int it = 0; it < 2; ++it) {
            int v = tid + it * 256;
            int m = v >> 2;
            int kk = (v & 3) * 4;
            const float4 a = *reinterpret_cast<const float4*>(
                &ctx[(size_t)(m0 + m) * DIM + k0 + kk]);
            As[kk + 0][m] = a.x; As[kk + 1][m] = a.y;
            As[kk + 2][m] = a.z; As[kk + 3][m] = a.w;
        }
        #pragma unroll
        for (int it = 0; it < 2; ++it) {
            int v = tid + it * 256;
            int k = v >> 5;
            int n = (v & 31) * 4;
            *reinterpret_cast<float4*>(&Bs[k][n]) =
                *reinterpret_cast<const float4*>(&w[(size_t)(k0 + k) * DIM + n0 + n]);
        }
        __syncthreads();

        #pragma unroll
        for (int k = 0; k < 16; ++k) {
            const float4 a0 = *reinterpret_cast<const float4*>(&As[k][ty * 4]);
            const float4 a1 = *reinterpret_cast<const float4*>(&As[k][64 + ty * 4]);
            const float4 b0 = *reinterpret_cast<const float4*>(&Bs[k][tx * 4]);
            const float4 b1 = *reinterpret_cast<const float4*>(&Bs[k][64 + tx * 4]);
            const float av[2][4] = {{a0.x, a0.y, a0.z, a0.w}, {a1.x, a1.y, a1.z, a1.w}};
            const float bv[2][4] = {{b0.x, b0.y, b0.z, b0.w}, {b1.x, b1.y, b1.z, b1.w}};
            #pragma unroll
            for (int ii = 0; ii < 2; ++ii)
                #pragma unroll
                for (int jj = 0; jj < 2; ++jj)
                    #pragma unroll
                    for (int i = 0; i < 4; ++i)
                        #pragma unroll
                        for (int j = 0; j < 4; ++j)
                            acc[ii][jj][i][j] = fmaf(av[ii][i], bv[jj][j], acc[ii][jj][i][j]);
        }
        __syncthreads();
    }

    #pragma unroll
    for (int ii = 0; ii < 2; ++ii) {
        #pragma unroll
        for (int jj = 0; jj < 2; ++jj) {
            const int n = n0 + jj * 64 + tx * 4;
            const float4 bb = *reinterpret_cast<const float4*>(&bias[n]);
            #pragma unroll
            for (int i = 0; i < 4; ++i) {
                const int m = m0 + ii * 64 + ty * 4 + i;
                float4 r;
                r.x = acc[ii][jj][i][0] + bb.x;
                r.y = acc[ii][jj][i][1] + bb.y;
                r.z = acc[ii][jj][i][2] + bb.z;
                r.w = acc[ii][jj][i][3] + bb.w;
                *reinterpret_cast<float4*>(&out[(size_t)m * DIM + n]) = r;
            }
        }
    }
}

// ---------------------------------------------------------------------------
// Launch. Workspace layout (fp32):
//   [0)        Q   [B,H,S,64]   25.2 MB
//   [QSZ)      K   same
//   [2*QSZ)    V   same
//   [3*QSZ)    ctx [B,S,D]      25.2 MB
// total ~100.7 MB required in d_ws.
// ---------------------------------------------------------------------------
extern "C" void kernel_launch(void* const* d_in, const int* in_sizes, int n_in,
                              void* d_out, int out_size, void* d_ws, size_t ws_size,
                              hipStream_t stream)
{
    const float* x     = (const float*)d_in[0];
    const float* w_qkv = (const float*)d_in[1];
    const float* b_qkv = (const float*)d_in[2];
    const float* w_out = (const float*)d_in[3];
    const float* b_out = (const float*)d_in[4];
    float* out = (float*)d_out;
    float* ws  = (float*)d_ws;

    const size_t QSZ = (size_t)NB * HEADS * SEQ * HD;  // 6,291,456 floats
    float* ctx = ws + 3 * QSZ;

    qkv_gemm_kernel<<<dim3(NQKV / 128, (NB * SEQ) / 128), 256, 0, stream>>>(
        x, w_qkv, b_qkv, ws);
    attn_kernel<<<dim3(SEQ / 64, NB * HEADS), 256, 0, stream>>>(ws, ctx);
    out_gemm_kernel<<<dim3(DIM / 128, (NB * SEQ) / 128), 256, 0, stream>>>(
        ctx, w_out, b_out, out);
}

// Round 2
// 607.628 us; speedup vs baseline: 2.7051x; 2.7051x over previous
//
#include <hip/hip_runtime.h>
#include <cstdint>
#include <cstddef>

#define HEADS 12
#define HD    64
#define NB    4
#define SEQ   2048
#define DIM   768
#define NQKV  2304

static constexpr float SCALE = 0.28867513459481287f; // 1/sqrt(12) (per reference)

typedef __attribute__((ext_vector_type(8))) short short8;
typedef __attribute__((ext_vector_type(4))) short short4v;
typedef __attribute__((ext_vector_type(4))) float f32x4;

__device__ inline unsigned short f2bf(float x) {
    union { float f; uint32_t u; } v; v.f = x;
    return (unsigned short)((v.u + 0x7fffu + ((v.u >> 16) & 1u)) >> 16);
}

// ---------------------------------------------------------------------------
// Kernel 1: QKV projection GEMM (fp32 compute).
// C[8192][2304] = x[8192][768] @ w[768][2304] + b
// Epilogue emits bf16: Q [bh][s][hd] (pre-scaled by 1/sqrt(12)), K [bh][s][hd],
// and V^T [bh][hd][s] for the MFMA attention kernel.
// ---------------------------------------------------------------------------
__global__ __launch_bounds__(256) void qkv_gemm_kernel(
    const float* __restrict__ x, const float* __restrict__ w,
    const float* __restrict__ bias,
    unsigned short* __restrict__ qb, unsigned short* __restrict__ kbuf,
    unsigned short* __restrict__ vt)
{
    __shared__ __align__(16) float As[16][132]; // transposed: As[k][m]
    __shared__ __align__(16) float Bs[16][132]; // Bs[k][n]

    const int tid = threadIdx.x;
    const int tx = tid & 15, ty = tid >> 4;
    const int m0 = blockIdx.y * 128;
    const int n0 = blockIdx.x * 128;

    float acc[2][2][4][4] = {};

    for (int k0 = 0; k0 < DIM; k0 += 16) {
        #pragma unroll
        for (int it = 0; it < 2; ++it) {
            int v = tid + it * 256;
            int m = v >> 2;
            int kk = (v & 3) * 4;
            const float4 a = *reinterpret_cast<const float4*>(
                &x[(size_t)(m0 + m) * DIM + k0 + kk]);
            As[kk + 0][m] = a.x; As[kk + 1][m] = a.y;
            As[kk + 2][m] = a.z; As[kk + 3][m] = a.w;
        }
        #pragma unroll
        for (int it = 0; it < 2; ++it) {
            int v = tid + it * 256;
            int k = v >> 5;
            int n = (v & 31) * 4;
            *reinterpret_cast<float4*>(&Bs[k][n]) =
                *reinterpret_cast<const float4*>(&w[(size_t)(k0 + k) * NQKV + n0 + n]);
        }
        __syncthreads();

        #pragma unroll
        for (int k = 0; k < 16; ++k) {
            const float4 a0 = *reinterpret_cast<const float4*>(&As[k][ty * 4]);
            const float4 a1 = *reinterpret_cast<const float4*>(&As[k][64 + ty * 4]);
            const float4 b0 = *reinterpret_cast<const float4*>(&Bs[k][tx * 4]);
            const float4 b1 = *reinterpret_cast<const float4*>(&Bs[k][64 + tx * 4]);
            const float av[2][4] = {{a0.x, a0.y, a0.z, a0.w}, {a1.x, a1.y, a1.z, a1.w}};
            const float bv[2][4] = {{b0.x, b0.y, b0.z, b0.w}, {b1.x, b1.y, b1.z, b1.w}};
            #pragma unroll
            for (int ii = 0; ii < 2; ++ii)
                #pragma unroll
                for (int jj = 0; jj < 2; ++jj)
                    #pragma unroll
                    for (int i = 0; i < 4; ++i)
                        #pragma unroll
                        for (int j = 0; j < 4; ++j)
                            acc[ii][jj][i][j] = fmaf(av[ii][i], bv[jj][j], acc[ii][jj][i][j]);
        }
        __syncthreads();
    }

    // Epilogue: bias, bf16 convert, scatter.
    #pragma unroll
    for (int ii = 0; ii < 2; ++ii) {
        #pragma unroll
        for (int jj = 0; jj < 2; ++jj) {
            const int nb4 = n0 + jj * 64 + tx * 4;   // 4 contiguous cols, one head
            const int which = nb4 / DIM;             // 0=q 1=k 2=v (const per block)
            const int rem = nb4 - which * DIM;
            const int h = rem >> 6;
            const int dh = rem & 63;
            const float4 bb = *reinterpret_cast<const float4*>(&bias[nb4]);
            const float bj[4] = {bb.x, bb.y, bb.z, bb.w};

            if (which == 2) {
                // V^T [bh][hd][s]: pack 4 consecutive s per hd
                const int m = m0 + ii * 64 + ty * 4;
                const int b_ = m >> 11;
                const int s_ = m & 2047;
                #pragma unroll
                for (int j = 0; j < 4; ++j) {
                    short4v pk;
                    #pragma unroll
                    for (int i = 0; i < 4; ++i)
                        pk[i] = (short)f2bf(acc[ii][jj][i][j] + bj[j]);
                    *reinterpret_cast<short4v*>(
                        vt + ((size_t)(b_ * HEADS + h) * HD + dh + j) * SEQ + s_) = pk;
                }
            } else {
                const float sc = (which == 0) ? SCALE : 1.0f;
                unsigned short* dst0 = (which == 0) ? qb : kbuf;
                #pragma unroll
                for (int i = 0; i < 4; ++i) {
                    const int m = m0 + ii * 64 + ty * 4 + i;
                    const int b_ = m >> 11;
                    const int s_ = m & 2047;
                    short4v pk;
                    #pragma unroll
                    for (int j = 0; j < 4; ++j)
                        pk[j] = (short)f2bf((acc[ii][jj][i][j] + bj[j]) * sc);
                    *reinterpret_cast<short4v*>(
                        dst0 + ((size_t)(b_ * HEADS + h) * SEQ + s_) * HD + dh) = pk;
                }
            }
        }
    }
}

// ---------------------------------------------------------------------------
// Kernel 2: flash attention on bf16 MFMA (16x16x32), swapped-QK^T.
// Block = (b,h) x 64 q-rows; 4 waves x 16 q-rows each. KVBLK=64.
// S^T = K·Q^T  (lane owns q = lane&15 -> softmax = local reduce + 2 shfl_xor).
// P staged per-wave in LDS (XOR-swizzled); PV via V^T tile.
// ---------------------------------------------------------------------------
__global__ __launch_bounds__(256) void attn_kernel(
    const unsigned short* __restrict__ qb, const unsigned short* __restrict__ kbuf,
    const unsigned short* __restrict__ vt, float* __restrict__ ctx)
{
    __shared__ __align__(16) unsigned short Ks[64][64];  // [key][hd], chunk-swizzled
    __shared__ __align__(16) unsigned short Vs[64][64];  // [hd][key], chunk-swizzled
    __shared__ __align__(16) unsigned short Ps[4][16][64]; // per-wave [q][key], swz

    const int tid = threadIdx.x;
    const int wave = tid >> 6;
    const int lane = tid & 63;
    const int col = lane & 15;   // q index (B-frag n / A-frag m)
    const int g   = lane >> 4;   // k-chunk group
    const int bh = blockIdx.y;
    const int q0 = blockIdx.x * 64;
    const int wq = q0 + wave * 16 + col;

    const size_t hb = (size_t)bh * SEQ * HD;

    // Q B-fragments (global, bf16, pre-scaled): lane holds Q[wq][8g+e (+32)]
    short8 qf[2];
    {
        const unsigned short* src = qb + hb + (size_t)wq * HD + g * 8;
        qf[0] = *reinterpret_cast<const short8*>(src);
        qf[1] = *reinterpret_cast<const short8*>(src + 32);
    }

    f32x4 acc4[4] = {};             // PV acc: rows q=4g+r, cols hd=16nb+col
    float m_run = -INFINITY, l_run = 0.0f;

    const unsigned short* Kg = kbuf + hb;          // [key][hd]
    const unsigned short* Vg = vt + hb;            // [hd][s]

    for (int jt = 0; jt < SEQ / 64; ++jt) {
        const int kb0 = jt * 64;
        __syncthreads();
        #pragma unroll
        for (int it = 0; it < 2; ++it) {
            int v = tid + it * 256;
            int row = v >> 3;
            int c = v & 7;
            *reinterpret_cast<short8*>(&Ks[row][((c ^ (row & 7)) << 3)]) =
                *reinterpret_cast<const short8*>(Kg + (size_t)(kb0 + row) * HD + c * 8);
            *reinterpret_cast<short8*>(&Vs[row][((c ^ (row & 7)) << 3)]) =
                *reinterpret_cast<const short8*>(Vg + (size_t)row * SEQ + kb0 + c * 8);
        }
        __syncthreads();

        // S^T = K · Q^T   (4 key-blocks of 16, 2 k-steps over hd)
        f32x4 st[4] = {};
        #pragma unroll
        for (int m = 0; m < 4; ++m) {
            const int row = m * 16 + col;
            const short8 kf0 = *reinterpret_cast<const short8*>(
                &Ks[row][((g ^ (col & 7)) << 3)]);
            const short8 kf1 = *reinterpret_cast<const short8*>(
                &Ks[row][(((g + 4) ^ (col & 7)) << 3)]);
            st[m] = __builtin_amdgcn_mfma_f32_16x16x32_bf16(kf0, qf[0], st[m], 0, 0, 0);
            st[m] = __builtin_amdgcn_mfma_f32_16x16x32_bf16(kf1, qf[1], st[m], 0, 0, 0);
        }

        // online softmax for q=col over 64 keys
        float tmax = -INFINITY;
        #pragma unroll
        for (int m = 0; m < 4; ++m)
            #pragma unroll
            for (int r = 0; r < 4; ++r)
                tmax = fmaxf(tmax, st[m][r]);
        tmax = fmaxf(tmax, __shfl_xor(tmax, 16));
        tmax = fmaxf(tmax, __shfl_xor(tmax, 32));
        const float m_new = fmaxf(m_run, tmax);

        float p[4][4];
        float rs = 0.0f;
        #pragma unroll
        for (int m = 0; m < 4; ++m)
            #pragma unroll
            for (int r = 0; r < 4; ++r) {
                p[m][r] = __expf(st[m][r] - m_new);
                rs += p[m][r];
            }
        rs += __shfl_xor(rs, 16);
        rs += __shfl_xor(rs, 32);
        const float alpha = __expf(m_run - m_new);  // first tile: exp(-inf)=0
        l_run = l_run * alpha + rs;
        m_run = m_new;

        // rescale acc rows (row q = 4g + r; alpha lives in lane q)
        float af[4];
        #pragma unroll
        for (int r = 0; r < 4; ++r) af[r] = __shfl(alpha, g * 4 + r);
        #pragma unroll
        for (int nb = 0; nb < 4; ++nb)
            #pragma unroll
            for (int r = 0; r < 4; ++r)
                acc4[nb][r] *= af[r];

        // stage P (bf16) to per-wave LDS [q][key], swizzled; keys 16m+4g+r
        #pragma unroll
        for (int m = 0; m < 4; ++m) {
            short4v pk;
            #pragma unroll
            for (int r = 0; r < 4; ++r) pk[r] = (short)f2bf(p[m][r]);
            const int sc = (2 * m + (g >> 1)) ^ (col & 7);
            *reinterpret_cast<short4v*>(
                &Ps[wave][col][(sc << 3) + ((g & 1) << 2)]) = pk;
        }

        // P A-fragments: lane holds P[q=col][8g+e (+32)]
        const short8 pf0 = *reinterpret_cast<const short8*>(
            &Ps[wave][col][((g ^ (col & 7)) << 3)]);
        const short8 pf1 = *reinterpret_cast<const short8*>(
            &Ps[wave][col][(((g + 4) ^ (col & 7)) << 3)]);

        // acc += P @ V   (4 hd-blocks of 16, 2 k-steps over keys)
        #pragma unroll
        for (int nb = 0; nb < 4; ++nb) {
            const int row = nb * 16 + col;
            const short8 vf0 = *reinterpret_cast<const short8*>(
                &Vs[row][((g ^ (col & 7)) << 3)]);
            const short8 vf1 = *reinterpret_cast<const short8*>(
                &Vs[row][(((g + 4) ^ (col & 7)) << 3)]);
            acc4[nb] = __builtin_amdgcn_mfma_f32_16x16x32_bf16(pf0, vf0, acc4[nb], 0, 0, 0);
            acc4[nb] = __builtin_amdgcn_mfma_f32_16x16x32_bf16(pf1, vf1, acc4[nb], 0, 0, 0);
        }
    }

    // epilogue: normalize, write ctx fp32 [B,S,D] (d = h*64 + hd)
    float lr[4];
    #pragma unroll
    for (int r = 0; r < 4; ++r) lr[r] = 1.0f / __shfl(l_run, g * 4 + r);
    const int b_ = bh / HEADS;
    const int h = bh - b_ * HEADS;
    #pragma unroll
    for (int nb = 0; nb < 4; ++nb)
        #pragma unroll
        for (int r = 0; r < 4; ++r) {
            const int s_ = q0 + wave * 16 + g * 4 + r;
            ctx[((size_t)b_ * SEQ + s_) * DIM + h * HD + nb * 16 + col] =
                acc4[nb][r] * lr[r];
        }
}

// ---------------------------------------------------------------------------
// Kernel 3: output projection GEMM (fp32). out = ctx @ w_out + b_out
// ---------------------------------------------------------------------------
__global__ __launch_bounds__(256) void out_gemm_kernel(
    const float* __restrict__ ctx, const float* __restrict__ w,
    const float* __restrict__ bias, float* __restrict__ out)
{
    __shared__ __align__(16) float As[16][132];
    __shared__ __align__(16) float Bs[16][132];

    const int tid = threadIdx.x;
    const int tx = tid & 15, ty = tid >> 4;
    const int m0 = blockIdx.y * 128;
    const int n0 = blockIdx.x * 128;

    float acc[2][2][4][4] = {};

    for (int k0 = 0; k0 < DIM; k0 += 16) {
        #pragma unroll
        for (int it = 0; it < 2; ++it) {
            int v = tid + it * 256;
            int m = v >> 2;
            int kk = (v & 3) * 4;
            const float4 a = *reinterpret_cast<const float4*>(
                &ctx[(size_t)(m0 + m) * DIM + k0 + kk]);
            As[kk + 0][m] = a.x; As[kk + 1][m] = a.y;
            As[kk + 2][m] = a.z; As[kk + 3][m] = a.w;
        }
        #pragma unroll
        for (int it = 0; it < 2; ++it) {
            int v = tid + it * 256;
            int k = v >> 5;
            int n = (v & 31) * 4;
            *reinterpret_cast<float4*>(&Bs[k][n]) =
                *reinterpret_cast<const float4*>(&w[(size_t)(k0 + k) * DIM + n0 + n]);
        }
        __syncthreads();

        #pragma unroll
        for (int k = 0; k < 16; ++k) {
            const float4 a0 = *reinterpret_cast<const float4*>(&As[k][ty * 4]);
            const float4 a1 = *reinterpret_cast<const float4*>(&As[k][64 + ty * 4]);
            const float4 b0 = *reinterpret_cast<const float4*>(&Bs[k][tx * 4]);
            const float4 b1 = *reinterpret_cast<const float4*>(&Bs[k][64 + tx * 4]);
            const float av[2][4] = {{a0.x, a0.y, a0.z, a0.w}, {a1.x, a1.y, a1.z, a1.w}};
            const float bv[2][4] = {{b0.x, b0.y, b0.z, b0.w}, {b1.x, b1.y, b1.z, b1.w}};
            #pragma unroll
            for (int ii = 0; ii < 2; ++ii)
                #pragma unroll
                for (int jj = 0; jj < 2; ++jj)
                    #pragma unroll
                    for (int i = 0; i < 4; ++i)
                        #pragma unroll
                        for (int j = 0; j < 4; ++j)
                            acc[ii][jj][i][j] = fmaf(av[ii][i], bv[jj][j], acc[ii][jj][i][j]);
        }
        __syncthreads();
    }

    #pragma unroll
    for (int ii = 0; ii < 2; ++ii) {
        #pragma unroll
        for (int jj = 0; jj < 2; ++jj) {
            const int n = n0 + jj * 64 + tx * 4;
            const float4 bb = *reinterpret_cast<const float4*>(&bias[n]);
            #pragma unroll
            for (int i = 0; i < 4; ++i) {
                const int m = m0 + ii * 64 + ty * 4 + i;
                float4 r;
                r.x = acc[ii][jj][i][0] + bb.x;
                r.y = acc[ii][jj][i][1] + bb.y;
                r.z = acc[ii][jj][i][2] + bb.z;
                r.w = acc[ii][jj][i][3] + bb.w;
                *reinterpret_cast<float4*>(&out[(size_t)m * DIM + n]) = r;
            }
        }
    }
}

// ---------------------------------------------------------------------------
// Workspace layout:
//   qb  bf16 [48][2048][64]   12.58 MB  (pre-scaled Q)
//   kb  bf16 [48][2048][64]   12.58 MB
//   vt  bf16 [48][64][2048]   12.58 MB  (V transposed)
//   ctx fp32 [4][2048][768]   25.17 MB
// total ~62.9 MB
// ---------------------------------------------------------------------------
extern "C" void kernel_launch(void* const* d_in, const int* in_sizes, int n_in,
                              void* d_out, int out_size, void* d_ws, size_t ws_size,
                              hipStream_t stream)
{
    const float* x     = (const float*)d_in[0];
    const float* w_qkv = (const float*)d_in[1];
    const float* b_qkv = (const float*)d_in[2];
    const float* w_out = (const float*)d_in[3];
    const float* b_out = (const float*)d_in[4];
    float* out = (float*)d_out;

    const size_t QSZ = (size_t)NB * HEADS * SEQ * HD;  // 6,291,456 elements
    unsigned short* qb = (unsigned short*)d_ws;
    unsigned short* kb = qb + QSZ;
    unsigned short* vt = kb + QSZ;
    float* ctx = (float*)(vt + QSZ);

    qkv_gemm_kernel<<<dim3(NQKV / 128, (NB * SEQ) / 128), 256, 0, stream>>>(
        x, w_qkv, b_qkv, qb, kb, vt);
    attn_kernel<<<dim3(SEQ / 64, NB * HEADS), 256, 0, stream>>>(qb, kb, vt, ctx);
    out_gemm_kernel<<<dim3(DIM / 128, (NB * SEQ) / 128), 256, 0, stream>>>(
        ctx, w_out, b_out, out);
}

// Round 3
// 203.184 us; speedup vs baseline: 8.0897x; 2.9905x over previous
//
#include <hip/hip_runtime.h>
#include <cstdint>
#include <cstddef>

#define HEADS 12
#define HD    64
#define NB    4
#define SEQ   2048
#define DIM   768
#define NQKV  2304

static constexpr float SCALE = 0.28867513459481287f; // 1/sqrt(12) (per reference)

typedef __attribute__((ext_vector_type(8))) short short8;
typedef __attribute__((ext_vector_type(4))) short short4v;
typedef __attribute__((ext_vector_type(4))) float f32x4;

__device__ inline unsigned short f2bf(float x) {
    union { float f; uint32_t u; } v; v.f = x;
    return (unsigned short)((v.u + 0x7fffu + ((v.u >> 16) & 1u)) >> 16);
}

__device__ inline void gload16(const void* g, const void* l) {
    __builtin_amdgcn_global_load_lds(
        (const __attribute__((address_space(1))) unsigned int*)g,
        (__attribute__((address_space(3))) unsigned int*)(size_t)(
            (const __attribute__((address_space(0))) char*)l -
            (const __attribute__((address_space(0))) char*)nullptr) == nullptr
            ? nullptr : (__attribute__((address_space(3))) unsigned int*)(l),
        16, 0, 0);
}

// simpler, canonical form (the above guard never triggers; keep direct cast)
__device__ inline void gld16(const void* g, void* l) {
    __builtin_amdgcn_global_load_lds(
        (const __attribute__((address_space(1))) unsigned int*)g,
        (__attribute__((address_space(3))) unsigned int*)l, 16, 0, 0);
}

// ---------------------------------------------------------------------------
// Convert kernels (memory-bound, run once, ~10 us total)
// ---------------------------------------------------------------------------
__global__ __launch_bounds__(256) void convert_x_kernel(
    const float* __restrict__ x, unsigned short* __restrict__ xb)
{
    const size_t i = ((size_t)blockIdx.x * 256 + threadIdx.x) * 8;
    const float4 a = *reinterpret_cast<const float4*>(x + i);
    const float4 b = *reinterpret_cast<const float4*>(x + i + 4);
    short8 o;
    o[0] = (short)f2bf(a.x); o[1] = (short)f2bf(a.y);
    o[2] = (short)f2bf(a.z); o[3] = (short)f2bf(a.w);
    o[4] = (short)f2bf(b.x); o[5] = (short)f2bf(b.y);
    o[6] = (short)f2bf(b.z); o[7] = (short)f2bf(b.w);
    *reinterpret_cast<short8*>(xb + i) = o;
}

// w [K][N] fp32  ->  wT [N][K] bf16   (64x64 tiles)
__global__ __launch_bounds__(256) void transpose_w_kernel(
    const float* __restrict__ w, unsigned short* __restrict__ wT,
    int ncols /*N*/, int nrows /*K*/)
{
    __shared__ float tile[64][65];
    const int k0 = blockIdx.y * 64;
    const int n0 = blockIdx.x * 64;
    const int tr = threadIdx.x >> 4;
    const int tc4 = (threadIdx.x & 15) * 4;
    #pragma unroll
    for (int it = 0; it < 4; ++it) {
        const int kk = tr + it * 16;
        *reinterpret_cast<float4*>(&tile[kk][tc4]) =
            *reinterpret_cast<const float4*>(w + (size_t)(k0 + kk) * ncols + n0 + tc4);
    }
    __syncthreads();
    #pragma unroll
    for (int it = 0; it < 4; ++it) {
        const int nn = tr + it * 16;
        short4v o;
        #pragma unroll
        for (int r = 0; r < 4; ++r) o[r] = (short)f2bf(tile[tc4 + r][nn]);
        *reinterpret_cast<short4v*>(wT + (size_t)(n0 + nn) * nrows + k0 + tc4) = o;
    }
}

// ---------------------------------------------------------------------------
// Kernel 1: QKV GEMM, bf16 MFMA (m97 structure).
// C[8192][2304] = xb[8192][768] @ wqT[2304][768]^T + bias
// 128x128 tile, BK=64, 4 waves (2x2 of 64x64), global_load_lds w=16,
// XOR chunk-swizzle (chunk ^ (row&7)) via pre-swizzled global source.
// Epilogue: bf16 scatter to qb [bh][s][64] (Q scaled), kb, vt [bh][hd][s].
// ---------------------------------------------------------------------------
__global__ __launch_bounds__(256) void qkv_gemm_bf16(
    const unsigned short* __restrict__ A,   // [8192][768]
    const unsigned short* __restrict__ BT,  // [2304][768]
    const float* __restrict__ bias,
    unsigned short* __restrict__ qb, unsigned short* __restrict__ kb,
    unsigned short* __restrict__ vt)
{
    __shared__ __align__(16) unsigned short As[128][64];
    __shared__ __align__(16) unsigned short Bs[128][64];

    const int tid = threadIdx.x;
    const int wave = tid >> 6;
    const int lane = tid & 63;
    const int col = lane & 15;
    const int g = lane >> 4;
    const int m0 = blockIdx.y * 128;
    const int n0 = blockIdx.x * 128;
    const int wr = wave >> 1, wc = wave & 1;

    const int srow = tid >> 3;   // staging row (0..31), +32/iter
    const int scl  = tid & 7;    // staging chunk-in-row

    f32x4 acc[4][4] = {};

    for (int kt = 0; kt < DIM; kt += 64) {
        __syncthreads();
        #pragma unroll
        for (int it = 0; it < 4; ++it) {
            const int row = srow + it * 32;
            const int cg = scl ^ (row & 7);
            gld16(A + (size_t)(m0 + row) * DIM + kt + cg * 8,
                  &As[0][0] + (size_t)(it * 256 + wave * 64) * 8);
            gld16(BT + (size_t)(n0 + row) * DIM + kt + cg * 8,
                  &Bs[0][0] + (size_t)(it * 256 + wave * 64) * 8);
        }
        __syncthreads();

        #pragma unroll
        for (int ks = 0; ks < 2; ++ks) {
            short8 af[4], bf[4];
            #pragma unroll
            for (int i = 0; i < 4; ++i) {
                const int ra = wr * 64 + i * 16 + col;
                af[i] = *reinterpret_cast<const short8*>(
                    &As[ra][(((ks * 4 + g) ^ (ra & 7)) << 3)]);
                const int rb = wc * 64 + i * 16 + col;
                bf[i] = *reinterpret_cast<const short8*>(
                    &Bs[rb][(((ks * 4 + g) ^ (rb & 7)) << 3)]);
            }
            #pragma unroll
            for (int i = 0; i < 4; ++i)
                #pragma unroll
                for (int j = 0; j < 4; ++j)
                    acc[i][j] = __builtin_amdgcn_mfma_f32_16x16x32_bf16(
                        af[i], bf[j], acc[i][j], 0, 0, 0);
        }
    }

    // Epilogue: bias + bf16 scatter.  which is block-uniform (768 % 128 == 0).
    const int which = n0 / DIM;
    #pragma unroll
    for (int j = 0; j < 4; ++j) {
        const int n = n0 + wc * 64 + j * 16 + col;
        const int rem = n - which * DIM;
        const int h = rem >> 6, dh = rem & 63;
        const float bj = bias[n];
        #pragma unroll
        for (int i = 0; i < 4; ++i) {
            const int mbase = m0 + wr * 64 + i * 16 + g * 4;
            const int b_ = mbase >> 11;
            const int s_ = mbase & 2047;
            const size_t bh = (size_t)(b_ * HEADS + h);
            if (which == 2) {
                short4v pk;
                #pragma unroll
                for (int r = 0; r < 4; ++r)
                    pk[r] = (short)f2bf(acc[i][j][r] + bj);
                *reinterpret_cast<short4v*>(vt + (bh * HD + dh) * SEQ + s_) = pk;
            } else {
                unsigned short* dst = (which == 0) ? qb : kb;
                const float sc = (which == 0) ? SCALE : 1.0f;
                #pragma unroll
                for (int r = 0; r < 4; ++r)
                    dst[(bh * SEQ + s_ + r) * HD + dh] =
                        f2bf((acc[i][j][r] + bj) * sc);
            }
        }
    }
}

// ---------------------------------------------------------------------------
// Kernel 2: flash attention on bf16 MFMA (unchanged math; ctx now bf16 out).
// ---------------------------------------------------------------------------
__global__ __launch_bounds__(256) void attn_kernel(
    const unsigned short* __restrict__ qb, const unsigned short* __restrict__ kbuf,
    const unsigned short* __restrict__ vt, unsigned short* __restrict__ ctxb)
{
    __shared__ __align__(16) unsigned short Ks[64][64];
    __shared__ __align__(16) unsigned short Vs[64][64];
    __shared__ __align__(16) unsigned short Ps[4][16][64];

    const int tid = threadIdx.x;
    const int wave = tid >> 6;
    const int lane = tid & 63;
    const int col = lane & 15;
    const int g   = lane >> 4;
    const int bh = blockIdx.y;
    const int q0 = blockIdx.x * 64;
    const int wq = q0 + wave * 16 + col;

    const size_t hb = (size_t)bh * SEQ * HD;

    short8 qf[2];
    {
        const unsigned short* src = qb + hb + (size_t)wq * HD + g * 8;
        qf[0] = *reinterpret_cast<const short8*>(src);
        qf[1] = *reinterpret_cast<const short8*>(src + 32);
    }

    f32x4 acc4[4] = {};
    float m_run = -INFINITY, l_run = 0.0f;

    const unsigned short* Kg = kbuf + hb;
    const unsigned short* Vg = vt + hb;

    for (int jt = 0; jt < SEQ / 64; ++jt) {
        const int kb0 = jt * 64;
        __syncthreads();
        #pragma unroll
        for (int it = 0; it < 2; ++it) {
            int v = tid + it * 256;
            int row = v >> 3;
            int c = v & 7;
            *reinterpret_cast<short8*>(&Ks[row][((c ^ (row & 7)) << 3)]) =
                *reinterpret_cast<const short8*>(Kg + (size_t)(kb0 + row) * HD + c * 8);
            *reinterpret_cast<short8*>(&Vs[row][((c ^ (row & 7)) << 3)]) =
                *reinterpret_cast<const short8*>(Vg + (size_t)row * SEQ + kb0 + c * 8);
        }
        __syncthreads();

        f32x4 st[4] = {};
        #pragma unroll
        for (int m = 0; m < 4; ++m) {
            const int row = m * 16 + col;
            const short8 kf0 = *reinterpret_cast<const short8*>(
                &Ks[row][((g ^ (col & 7)) << 3)]);
            const short8 kf1 = *reinterpret_cast<const short8*>(
                &Ks[row][(((g + 4) ^ (col & 7)) << 3)]);
            st[m] = __builtin_amdgcn_mfma_f32_16x16x32_bf16(kf0, qf[0], st[m], 0, 0, 0);
            st[m] = __builtin_amdgcn_mfma_f32_16x16x32_bf16(kf1, qf[1], st[m], 0, 0, 0);
        }

        float tmax = -INFINITY;
        #pragma unroll
        for (int m = 0; m < 4; ++m)
            #pragma unroll
            for (int r = 0; r < 4; ++r)
                tmax = fmaxf(tmax, st[m][r]);
        tmax = fmaxf(tmax, __shfl_xor(tmax, 16));
        tmax = fmaxf(tmax, __shfl_xor(tmax, 32));
        const float m_new = fmaxf(m_run, tmax);

        float p[4][4];
        float rs = 0.0f;
        #pragma unroll
        for (int m = 0; m < 4; ++m)
            #pragma unroll
            for (int r = 0; r < 4; ++r) {
                p[m][r] = __expf(st[m][r] - m_new);
                rs += p[m][r];
            }
        rs += __shfl_xor(rs, 16);
        rs += __shfl_xor(rs, 32);
        const float alpha = __expf(m_run - m_new);
        l_run = l_run * alpha + rs;
        m_run = m_new;

        float af[4];
        #pragma unroll
        for (int r = 0; r < 4; ++r) af[r] = __shfl(alpha, g * 4 + r);
        #pragma unroll
        for (int nb = 0; nb < 4; ++nb)
            #pragma unroll
            for (int r = 0; r < 4; ++r)
                acc4[nb][r] *= af[r];

        #pragma unroll
        for (int m = 0; m < 4; ++m) {
            short4v pk;
            #pragma unroll
            for (int r = 0; r < 4; ++r) pk[r] = (short)f2bf(p[m][r]);
            const int sc = (2 * m + (g >> 1)) ^ (col & 7);
            *reinterpret_cast<short4v*>(
                &Ps[wave][col][(sc << 3) + ((g & 1) << 2)]) = pk;
        }

        const short8 pf0 = *reinterpret_cast<const short8*>(
            &Ps[wave][col][((g ^ (col & 7)) << 3)]);
        const short8 pf1 = *reinterpret_cast<const short8*>(
            &Ps[wave][col][(((g + 4) ^ (col & 7)) << 3)]);

        #pragma unroll
        for (int nb = 0; nb < 4; ++nb) {
            const int row = nb * 16 + col;
            const short8 vf0 = *reinterpret_cast<const short8*>(
                &Vs[row][((g ^ (col & 7)) << 3)]);
            const short8 vf1 = *reinterpret_cast<const short8*>(
                &Vs[row][(((g + 4) ^ (col & 7)) << 3)]);
            acc4[nb] = __builtin_amdgcn_mfma_f32_16x16x32_bf16(pf0, vf0, acc4[nb], 0, 0, 0);
            acc4[nb] = __builtin_amdgcn_mfma_f32_16x16x32_bf16(pf1, vf1, acc4[nb], 0, 0, 0);
        }
    }

    float lr[4];
    #pragma unroll
    for (int r = 0; r < 4; ++r) lr[r] = 1.0f / __shfl(l_run, g * 4 + r);
    const int b_ = bh / HEADS;
    const int h = bh - b_ * HEADS;
    #pragma unroll
    for (int nb = 0; nb < 4; ++nb)
        #pragma unroll
        for (int r = 0; r < 4; ++r) {
            const int s_ = q0 + wave * 16 + g * 4 + r;
            ctxb[((size_t)b_ * SEQ + s_) * DIM + h * HD + nb * 16 + col] =
                f2bf(acc4[nb][r] * lr[r]);
        }
}

// ---------------------------------------------------------------------------
// Kernel 3: output projection, bf16 MFMA.  out = ctxb @ woT^T + b_out (fp32 out)
// ---------------------------------------------------------------------------
__global__ __launch_bounds__(256) void out_gemm_bf16(
    const unsigned short* __restrict__ A,   // ctxb [8192][768]
    const unsigned short* __restrict__ BT,  // woT  [768][768]
    const float* __restrict__ bias, float* __restrict__ out)
{
    __shared__ __align__(16) unsigned short As[128][64];
    __shared__ __align__(16) unsigned short Bs[128][64];

    const int tid = threadIdx.x;
    const int wave = tid >> 6;
    const int lane = tid & 63;
    const int col = lane & 15;
    const int g = lane >> 4;
    const int m0 = blockIdx.y * 128;
    const int n0 = blockIdx.x * 128;
    const int wr = wave >> 1, wc = wave & 1;

    const int srow = tid >> 3;
    const int scl  = tid & 7;

    f32x4 acc[4][4] = {};

    for (int kt = 0; kt < DIM; kt += 64) {
        __syncthreads();
        #pragma unroll
        for (int it = 0; it < 4; ++it) {
            const int row = srow + it * 32;
            const int cg = scl ^ (row & 7);
            gld16(A + (size_t)(m0 + row) * DIM + kt + cg * 8,
                  &As[0][0] + (size_t)(it * 256 + wave * 64) * 8);
            gld16(BT + (size_t)(n0 + row) * DIM + kt + cg * 8,
                  &Bs[0][0] + (size_t)(it * 256 + wave * 64) * 8);
        }
        __syncthreads();

        #pragma unroll
        for (int ks = 0; ks < 2; ++ks) {
            short8 af[4], bf[4];
            #pragma unroll
            for (int i = 0; i < 4; ++i) {
                const int ra = wr * 64 + i * 16 + col;
                af[i] = *reinterpret_cast<const short8*>(
                    &As[ra][(((ks * 4 + g) ^ (ra & 7)) << 3)]);
                const int rb = wc * 64 + i * 16 + col;
                bf[i] = *reinterpret_cast<const short8*>(
                    &Bs[rb][(((ks * 4 + g) ^ (rb & 7)) << 3)]);
            }
            #pragma unroll
            for (int i = 0; i < 4; ++i)
                #pragma unroll
                for (int j = 0; j < 4; ++j)
                    acc[i][j] = __builtin_amdgcn_mfma_f32_16x16x32_bf16(
                        af[i], bf[j], acc[i][j], 0, 0, 0);
        }
    }

    #pragma unroll
    for (int j = 0; j < 4; ++j) {
        const int n = n0 + wc * 64 + j * 16 + col;
        const float bj = bias[n];
        #pragma unroll
        for (int i = 0; i < 4; ++i) {
            const int m = m0 + wr * 64 + i * 16 + g * 4;
            #pragma unroll
            for (int r = 0; r < 4; ++r)
                out[(size_t)(m + r) * DIM + n] = acc[i][j][r] + bj;
        }
    }
}

// ---------------------------------------------------------------------------
// Workspace (bf16 elems unless noted):
//   qb   [48][2048][64]  6291456      kb   same          vt [48][64][2048] same
//   xb   [8192][768]     6291456      ctxb [8192][768]   6291456
//   wqT  [2304][768]     1769472      woT  [768][768]     589824
// total 33,816,576 ushorts = 67.6 MB
// ---------------------------------------------------------------------------
extern "C" void kernel_launch(void* const* d_in, const int* in_sizes, int n_in,
                              void* d_out, int out_size, void* d_ws, size_t ws_size,
                              hipStream_t stream)
{
    const float* x     = (const float*)d_in[0];
    const float* w_qkv = (const float*)d_in[1];
    const float* b_qkv = (const float*)d_in[2];
    const float* w_out = (const float*)d_in[3];
    const float* b_out = (const float*)d_in[4];
    float* out = (float*)d_out;

    const size_t QSZ = (size_t)NB * HEADS * SEQ * HD;  // 6,291,456
    unsigned short* qb   = (unsigned short*)d_ws;
    unsigned short* kb   = qb + QSZ;
    unsigned short* vt   = kb + QSZ;
    unsigned short* xb   = vt + QSZ;
    unsigned short* ctxb = xb + QSZ;
    unsigned short* wqT  = ctxb + QSZ;
    unsigned short* woT  = wqT + (size_t)NQKV * DIM;

    convert_x_kernel<<<3072, 256, 0, stream>>>(x, xb);
    transpose_w_kernel<<<dim3(NQKV / 64, DIM / 64), 256, 0, stream>>>(
        w_qkv, wqT, NQKV, DIM);
    transpose_w_kernel<<<dim3(DIM / 64, DIM / 64), 256, 0, stream>>>(
        w_out, woT, DIM, DIM);

    qkv_gemm_bf16<<<dim3(NQKV / 128, (NB * SEQ) / 128), 256, 0, stream>>>(
        xb, wqT, b_qkv, qb, kb, vt);
    attn_kernel<<<dim3(SEQ / 64, NB * HEADS), 256, 0, stream>>>(qb, kb, vt, ctxb);
    out_gemm_bf16<<<dim3(DIM / 128, (NB * SEQ) / 128), 256, 0, stream>>>(
        ctxb, woT, b_out, out);
}

// Round 4
// 172.243 us; speedup vs baseline: 9.5429x; 1.1796x over previous
//
#include <hip/hip_runtime.h>
#include <hip/hip_bf16.h>
#include <cstdint>
#include <cstddef>

#define HEADS 12
#define HD    64
#define NB    4
#define SEQ   2048
#define DIM   768
#define NQKV  2304

// Q pre-scale: (1/sqrt(HEADS)) * log2(e)  -> scores arrive in exp2 domain
static constexpr float QSCALE = 0.2886751345948129f * 1.4426950408889634f;

typedef __attribute__((ext_vector_type(8))) short short8;
typedef __attribute__((ext_vector_type(4))) short short4v;
typedef __attribute__((ext_vector_type(4))) float f32x4;

__device__ inline unsigned short f2bf(float x) {          // RNE, for cold paths
    union { float f; uint32_t u; } v; v.f = x;
    return (unsigned short)((v.u + 0x7fffu + ((v.u >> 16) & 1u)) >> 16);
}

__device__ inline unsigned short f2bf_fast(float x) {     // compiler hw-convert
    __hip_bfloat16 h = __float2bfloat16(x);
    unsigned short u;
    __builtin_memcpy(&u, &h, 2);
    return u;
}

__device__ inline void gld16(const void* g, void* l) {
    __builtin_amdgcn_global_load_lds(
        (const __attribute__((address_space(1))) unsigned int*)g,
        (__attribute__((address_space(3))) unsigned int*)l, 16, 0, 0);
}

// ---------------------------------------------------------------------------
// Convert kernels (memory-bound, run once)
// ---------------------------------------------------------------------------
__global__ __launch_bounds__(256) void convert_x_kernel(
    const float* __restrict__ x, unsigned short* __restrict__ xb)
{
    const size_t i = ((size_t)blockIdx.x * 256 + threadIdx.x) * 8;
    const float4 a = *reinterpret_cast<const float4*>(x + i);
    const float4 b = *reinterpret_cast<const float4*>(x + i + 4);
    short8 o;
    o[0] = (short)f2bf(a.x); o[1] = (short)f2bf(a.y);
    o[2] = (short)f2bf(a.z); o[3] = (short)f2bf(a.w);
    o[4] = (short)f2bf(b.x); o[5] = (short)f2bf(b.y);
    o[6] = (short)f2bf(b.z); o[7] = (short)f2bf(b.w);
    *reinterpret_cast<short8*>(xb + i) = o;
}

// w [K][N] fp32  ->  wT [N][K] bf16   (64x64 tiles)
__global__ __launch_bounds__(256) void transpose_w_kernel(
    const float* __restrict__ w, unsigned short* __restrict__ wT,
    int ncols /*N*/, int nrows /*K*/)
{
    __shared__ float tile[64][65];
    const int k0 = blockIdx.y * 64;
    const int n0 = blockIdx.x * 64;
    const int tr = threadIdx.x >> 4;
    const int tc4 = (threadIdx.x & 15) * 4;
    #pragma unroll
    for (int it = 0; it < 4; ++it) {
        const int kk = tr + it * 16;
        *reinterpret_cast<float4*>(&tile[kk][tc4]) =
            *reinterpret_cast<const float4*>(w + (size_t)(k0 + kk) * ncols + n0 + tc4);
    }
    __syncthreads();
    #pragma unroll
    for (int it = 0; it < 4; ++it) {
        const int nn = tr + it * 16;
        short4v o;
        #pragma unroll
        for (int r = 0; r < 4; ++r) o[r] = (short)f2bf(tile[tc4 + r][nn]);
        *reinterpret_cast<short4v*>(wT + (size_t)(n0 + nn) * nrows + k0 + tc4) = o;
    }
}

// ---------------------------------------------------------------------------
// Kernel 1: QKV GEMM, bf16 MFMA (m97 structure). Q scaled by QSCALE.
// ---------------------------------------------------------------------------
__global__ __launch_bounds__(256) void qkv_gemm_bf16(
    const unsigned short* __restrict__ A,   // [8192][768]
    const unsigned short* __restrict__ BT,  // [2304][768]
    const float* __restrict__ bias,
    unsigned short* __restrict__ qb, unsigned short* __restrict__ kb,
    unsigned short* __restrict__ vt)
{
    __shared__ __align__(16) unsigned short As[128][64];
    __shared__ __align__(16) unsigned short Bs[128][64];

    const int tid = threadIdx.x;
    const int wave = tid >> 6;
    const int lane = tid & 63;
    const int col = lane & 15;
    const int g = lane >> 4;
    const int m0 = blockIdx.y * 128;
    const int n0 = blockIdx.x * 128;
    const int wr = wave >> 1, wc = wave & 1;

    const int srow = tid >> 3;
    const int scl  = tid & 7;

    f32x4 acc[4][4] = {};

    for (int kt = 0; kt < DIM; kt += 64) {
        __syncthreads();
        #pragma unroll
        for (int it = 0; it < 4; ++it) {
            const int row = srow + it * 32;
            const int cg = scl ^ (row & 7);
            gld16(A + (size_t)(m0 + row) * DIM + kt + cg * 8,
                  &As[0][0] + (size_t)(it * 256 + wave * 64) * 8);
            gld16(BT + (size_t)(n0 + row) * DIM + kt + cg * 8,
                  &Bs[0][0] + (size_t)(it * 256 + wave * 64) * 8);
        }
        __syncthreads();

        #pragma unroll
        for (int ks = 0; ks < 2; ++ks) {
            short8 af[4], bf[4];
            #pragma unroll
            for (int i = 0; i < 4; ++i) {
                const int ra = wr * 64 + i * 16 + col;
                af[i] = *reinterpret_cast<const short8*>(
                    &As[ra][(((ks * 4 + g) ^ (ra & 7)) << 3)]);
                const int rb = wc * 64 + i * 16 + col;
                bf[i] = *reinterpret_cast<const short8*>(
                    &Bs[rb][(((ks * 4 + g) ^ (rb & 7)) << 3)]);
            }
            #pragma unroll
            for (int i = 0; i < 4; ++i)
                #pragma unroll
                for (int j = 0; j < 4; ++j)
                    acc[i][j] = __builtin_amdgcn_mfma_f32_16x16x32_bf16(
                        af[i], bf[j], acc[i][j], 0, 0, 0);
        }
    }

    const int which = n0 / DIM;
    #pragma unroll
    for (int j = 0; j < 4; ++j) {
        const int n = n0 + wc * 64 + j * 16 + col;
        const int rem = n - which * DIM;
        const int h = rem >> 6, dh = rem & 63;
        const float bj = bias[n];
        #pragma unroll
        for (int i = 0; i < 4; ++i) {
            const int mbase = m0 + wr * 64 + i * 16 + g * 4;
            const int b_ = mbase >> 11;
            const int s_ = mbase & 2047;
            const size_t bh = (size_t)(b_ * HEADS + h);
            if (which == 2) {
                short4v pk;
                #pragma unroll
                for (int r = 0; r < 4; ++r)
                    pk[r] = (short)f2bf(acc[i][j][r] + bj);
                *reinterpret_cast<short4v*>(vt + (bh * HD + dh) * SEQ + s_) = pk;
            } else {
                unsigned short* dst = (which == 0) ? qb : kb;
                const float sc = (which == 0) ? QSCALE : 1.0f;
                #pragma unroll
                for (int r = 0; r < 4; ++r)
                    dst[(bh * SEQ + s_ + r) * HD + dh] =
                        f2bf((acc[i][j][r] + bj) * sc);
            }
        }
    }
}

// ---------------------------------------------------------------------------
// Kernel 2: flash attention, bf16 MFMA, un-maxed exp2 softmax.
// Block = (b,h) x 64 q-rows; 4 waves x 16 q each. KVBLK=64.
// S^T = K·Q^T (scores already in log2 domain). p = exp2(s); no running max,
// no rescale. Row-sum reduced across lanes once, in the epilogue.
// K/V staged via global_load_lds w=16, inverse-swizzled source (rule 21).
// ---------------------------------------------------------------------------
__global__ __launch_bounds__(256) void attn_kernel(
    const unsigned short* __restrict__ qb, const unsigned short* __restrict__ kbuf,
    const unsigned short* __restrict__ vt, unsigned short* __restrict__ ctxb)
{
    __shared__ __align__(16) unsigned short Ks[64][64];  // [key][hd], chunk-swz
    __shared__ __align__(16) unsigned short Vs[64][64];  // [hd][key], chunk-swz
    __shared__ __align__(16) unsigned short Ps[4][16][64];

    const int tid = threadIdx.x;
    const int wave = tid >> 6;
    const int lane = tid & 63;
    const int col = lane & 15;
    const int g   = lane >> 4;
    const int bh = blockIdx.y;
    const int q0 = blockIdx.x * 64;
    const int wq = q0 + wave * 16 + col;

    const size_t hb = (size_t)bh * SEQ * HD;

    short8 qf[2];
    {
        const unsigned short* src = qb + hb + (size_t)wq * HD + g * 8;
        qf[0] = *reinterpret_cast<const short8*>(src);
        qf[1] = *reinterpret_cast<const short8*>(src + 32);
    }

    f32x4 acc4[4] = {};
    float l_part = 0.0f;     // this lane's partial row-sum (keys it owns)

    const unsigned short* Kg = kbuf + hb;
    const unsigned short* Vg = vt + hb;

    const int srow = tid >> 3;       // 0..31
    const int sc_  = tid & 7;

    for (int jt = 0; jt < SEQ / 64; ++jt) {
        const int kb0 = jt * 64;
        __syncthreads();
        #pragma unroll
        for (int it = 0; it < 2; ++it) {
            const int row = srow + it * 32;
            const int cg = sc_ ^ (row & 7);
            gld16(Kg + (size_t)(kb0 + row) * HD + cg * 8,
                  &Ks[0][0] + (size_t)(it * 256 + wave * 64) * 8);
            gld16(Vg + (size_t)row * SEQ + kb0 + cg * 8,
                  &Vs[0][0] + (size_t)(it * 256 + wave * 64) * 8);
        }
        __syncthreads();

        // S^T = K · Q^T
        f32x4 st[4] = {};
        #pragma unroll
        for (int m = 0; m < 4; ++m) {
            const int row = m * 16 + col;
            const short8 kf0 = *reinterpret_cast<const short8*>(
                &Ks[row][((g ^ (row & 7)) << 3)]);
            const short8 kf1 = *reinterpret_cast<const short8*>(
                &Ks[row][(((g + 4) ^ (row & 7)) << 3)]);
            st[m] = __builtin_amdgcn_mfma_f32_16x16x32_bf16(kf0, qf[0], st[m], 0, 0, 0);
            st[m] = __builtin_amdgcn_mfma_f32_16x16x32_bf16(kf1, qf[1], st[m], 0, 0, 0);
        }

        // p = exp2(s); accumulate partial row-sum; stage P as bf16
        float s0 = 0.0f, s1 = 0.0f, s2 = 0.0f, s3 = 0.0f;
        #pragma unroll
        for (int m = 0; m < 4; ++m) {
            float p[4];
            p[0] = __builtin_amdgcn_exp2f(st[m][0]);
            p[1] = __builtin_amdgcn_exp2f(st[m][1]);
            p[2] = __builtin_amdgcn_exp2f(st[m][2]);
            p[3] = __builtin_amdgcn_exp2f(st[m][3]);
            s0 += p[0]; s1 += p[1]; s2 += p[2]; s3 += p[3];
            short4v pk;
            #pragma unroll
            for (int r = 0; r < 4; ++r) pk[r] = (short)f2bf_fast(p[r]);
            const int scw = (2 * m + (g >> 1)) ^ (col & 7);
            *reinterpret_cast<short4v*>(
                &Ps[wave][col][(scw << 3) + ((g & 1) << 2)]) = pk;
        }
        l_part += (s0 + s1) + (s2 + s3);

        const short8 pf0 = *reinterpret_cast<const short8*>(
            &Ps[wave][col][((g ^ (col & 7)) << 3)]);
        const short8 pf1 = *reinterpret_cast<const short8*>(
            &Ps[wave][col][(((g + 4) ^ (col & 7)) << 3)]);

        // acc += P @ V
        #pragma unroll
        for (int nb = 0; nb < 4; ++nb) {
            const int row = nb * 16 + col;
            const short8 vf0 = *reinterpret_cast<const short8*>(
                &Vs[row][((g ^ (row & 7)) << 3)]);
            const short8 vf1 = *reinterpret_cast<const short8*>(
                &Vs[row][(((g + 4) ^ (row & 7)) << 3)]);
            acc4[nb] = __builtin_amdgcn_mfma_f32_16x16x32_bf16(pf0, vf0, acc4[nb], 0, 0, 0);
            acc4[nb] = __builtin_amdgcn_mfma_f32_16x16x32_bf16(pf1, vf1, acc4[nb], 0, 0, 0);
        }
    }

    // epilogue: one cross-lane row-sum reduce, normalize, write bf16 ctx
    float lt = l_part + __shfl_xor(l_part, 16);
    lt += __shfl_xor(lt, 32);
    float lr[4];
    #pragma unroll
    for (int r = 0; r < 4; ++r) lr[r] = 1.0f / __shfl(lt, g * 4 + r);
    const int b_ = bh / HEADS;
    const int h = bh - b_ * HEADS;
    #pragma unroll
    for (int nb = 0; nb < 4; ++nb)
        #pragma unroll
        for (int r = 0; r < 4; ++r) {
            const int s_ = q0 + wave * 16 + g * 4 + r;
            ctxb[((size_t)b_ * SEQ + s_) * DIM + h * HD + nb * 16 + col] =
                f2bf_fast(acc4[nb][r] * lr[r]);
        }
}

// ---------------------------------------------------------------------------
// Kernel 3: output projection, bf16 MFMA.  out = ctxb @ woT^T + b_out (fp32)
// ---------------------------------------------------------------------------
__global__ __launch_bounds__(256) void out_gemm_bf16(
    const unsigned short* __restrict__ A,   // ctxb [8192][768]
    const unsigned short* __restrict__ BT,  // woT  [768][768]
    const float* __restrict__ bias, float* __restrict__ out)
{
    __shared__ __align__(16) unsigned short As[128][64];
    __shared__ __align__(16) unsigned short Bs[128][64];

    const int tid = threadIdx.x;
    const int wave = tid >> 6;
    const int lane = tid & 63;
    const int col = lane & 15;
    const int g = lane >> 4;
    const int m0 = blockIdx.y * 128;
    const int n0 = blockIdx.x * 128;
    const int wr = wave >> 1, wc = wave & 1;

    const int srow = tid >> 3;
    const int scl  = tid & 7;

    f32x4 acc[4][4] = {};

    for (int kt = 0; kt < DIM; kt += 64) {
        __syncthreads();
        #pragma unroll
        for (int it = 0; it < 4; ++it) {
            const int row = srow + it * 32;
            const int cg = scl ^ (row & 7);
            gld16(A + (size_t)(m0 + row) * DIM + kt + cg * 8,
                  &As[0][0] + (size_t)(it * 256 + wave * 64) * 8);
            gld16(BT + (size_t)(n0 + row) * DIM + kt + cg * 8,
                  &Bs[0][0] + (size_t)(it * 256 + wave * 64) * 8);
        }
        __syncthreads();

        #pragma unroll
        for (int ks = 0; ks < 2; ++ks) {
            short8 af[4], bf[4];
            #pragma unroll
            for (int i = 0; i < 4; ++i) {
                const int ra = wr * 64 + i * 16 + col;
                af[i] = *reinterpret_cast<const short8*>(
                    &As[ra][(((ks * 4 + g) ^ (ra & 7)) << 3)]);
                const int rb = wc * 64 + i * 16 + col;
                bf[i] = *reinterpret_cast<const short8*>(
                    &Bs[rb][(((ks * 4 + g) ^ (rb & 7)) << 3)]);
            }
            #pragma unroll
            for (int i = 0; i < 4; ++i)
                #pragma unroll
                for (int j = 0; j < 4; ++j)
                    acc[i][j] = __builtin_amdgcn_mfma_f32_16x16x32_bf16(
                        af[i], bf[j], acc[i][j], 0, 0, 0);
        }
    }

    #pragma unroll
    for (int j = 0; j < 4; ++j) {
        const int n = n0 + wc * 64 + j * 16 + col;
        const float bj = bias[n];
        #pragma unroll
        for (int i = 0; i < 4; ++i) {
            const int m = m0 + wr * 64 + i * 16 + g * 4;
            #pragma unroll
            for (int r = 0; r < 4; ++r)
                out[(size_t)(m + r) * DIM + n] = acc[i][j][r] + bj;
        }
    }
}

// ---------------------------------------------------------------------------
// Workspace (ushort elems): qb/kb/vt/xb/ctxb 6291456 each; wqT 1769472; woT 589824
// total 33,816,576 ushorts = 67.6 MB
// ---------------------------------------------------------------------------
extern "C" void kernel_launch(void* const* d_in, const int* in_sizes, int n_in,
                              void* d_out, int out_size, void* d_ws, size_t ws_size,
                              hipStream_t stream)
{
    const float* x     = (const float*)d_in[0];
    const float* w_qkv = (const float*)d_in[1];
    const float* b_qkv = (const float*)d_in[2];
    const float* w_out = (const float*)d_in[3];
    const float* b_out = (const float*)d_in[4];
    float* out = (float*)d_out;

    const size_t QSZ = (size_t)NB * HEADS * SEQ * HD;  // 6,291,456
    unsigned short* qb   = (unsigned short*)d_ws;
    unsigned short* kb   = qb + QSZ;
    unsigned short* vt   = kb + QSZ;
    unsigned short* xb   = vt + QSZ;
    unsigned short* ctxb = xb + QSZ;
    unsigned short* wqT  = ctxb + QSZ;
    unsigned short* woT  = wqT + (size_t)NQKV * DIM;

    convert_x_kernel<<<3072, 256, 0, stream>>>(x, xb);
    transpose_w_kernel<<<dim3(NQKV / 64, DIM / 64), 256, 0, stream>>>(
        w_qkv, wqT, NQKV, DIM);
    transpose_w_kernel<<<dim3(DIM / 64, DIM / 64), 256, 0, stream>>>(
        w_out, woT, DIM, DIM);

    qkv_gemm_bf16<<<dim3(NQKV / 128, (NB * SEQ) / 128), 256, 0, stream>>>(
        xb, wqT, b_qkv, qb, kb, vt);
    attn_kernel<<<dim3(SEQ / 64, NB * HEADS), 256, 0, stream>>>(qb, kb, vt, ctxb);
    out_gemm_bf16<<<dim3(DIM / 128, (NB * SEQ) / 128), 256, 0, stream>>>(
        ctxb, woT, b_out, out);
}